// Round 3
// baseline (66.672 us; speedup 1.0000x reference)
//
#include <hip/hip_runtime.h>
#include <stdint.h>
#include <stddef.h>

// Problem constants
#define D_FEAT 1280
#define N_PAD  256
#define N_OUT  248
#define BM     32
#define BK     64
#define K_ITERS (D_FEAT / BK)          // 20
#define W_TILE_BYTES (N_PAD * BK * 2)  // 32 KB per K-tile of packed weights

typedef float f32x4 __attribute__((ext_vector_type(4)));
typedef short s16x8 __attribute__((ext_vector_type(8)));
typedef unsigned int u32x4 __attribute__((ext_vector_type(4)));

__device__ __forceinline__ unsigned short f2bf(float f) {
  union { float f; unsigned int u; } v; v.f = f;
  unsigned int r = (v.u + 0x7fffu + ((v.u >> 16) & 1u)) >> 16;
  return (unsigned short)r;
}

// one v_cvt_pk_bf16_f32: packs 2 fp32 -> 2 bf16 (RTNE), lo=a, hi=b
__device__ __forceinline__ unsigned int cvt_pk(float a, float b) {
  unsigned int r;
  asm("v_cvt_pk_bf16_f32 %0, %1, %2" : "=v"(r) : "v"(a), "v"(b));
  return r;
}

// ---------------------------------------------------------------------------
// Pack W_final (D,8), Wp1 (8,D,6), Wp2 (8,6,D,4) into one bf16 matrix laid out
// exactly as the main kernel's LDS B-tiles expect (XOR swizzle pre-baked so
// global_load_lds is a LINEAR copy and ds_read_b128 is conflict-free).
// ---------------------------------------------------------------------------
__global__ __launch_bounds__(256) void pack_w_kernel(
    const float* __restrict__ Wf, const float* __restrict__ Wp1,
    const float* __restrict__ Wp2, unsigned short* __restrict__ out) {
  int idx = blockIdx.x * 256 + threadIdx.x;    // 0 .. 20*256*64-1 = 327679
  int e = idx & 7;
  int chunk = idx >> 3;
  int s_phys = chunk & 7;
  int n = (chunk >> 3) & 255;
  int kt = chunk >> 11;
  int s_log = s_phys ^ (n & 7);
  int d = kt * BK + s_log * 8 + e;
  float v = 0.0f;
  if (n < 8) {
    v = Wf[d * 8 + n];
  } else if (n < 56) {
    int m = n - 8;
    v = Wp1[((m / 6) * D_FEAT + d) * 6 + (m % 6)];
  } else if (n < 248) {
    int m = n - 56;
    v = Wp2[(((m / 24) * 6 + ((m % 24) >> 2)) * D_FEAT + d) * 4 + (m & 3)];
  }
  out[idx] = f2bf(v);
}

// ---------------------------------------------------------------------------
// Fused GEMM (bf16 MFMA) + hierarchical softmax epilogue.
// Block: 256 threads = 4 waves, BM=32 rows. Waves split N only (1M x 4N):
// wave w owns rows 0..31 x cols 64w..64w+63 -> each B ds_read feeds 2 MFMAs.
// A: global->register fp32, v_cvt_pk_bf16_f32 in-reg. B: double-buffered LDS
// via global_load_lds with COUNTED vmcnt(8) + raw s_barrier per K-iter, so the
// 8 in-flight A prefetch loads are never drained at the barrier.
// ---------------------------------------------------------------------------
__global__ __launch_bounds__(256, 2) void tree_head_kernel(
    const float* __restrict__ x, const unsigned short* __restrict__ Wb,
    const float* __restrict__ b_final, const float* __restrict__ wu1,
    const float* __restrict__ b1, const float* __restrict__ wu2,
    const float* __restrict__ b2, float* __restrict__ out) {
  __shared__ char smem[65536];                 // 2 x 32KB B buffers; Ls aliases

  const int tid  = threadIdx.x;
  const int lane = tid & 63;
  const int wave = tid >> 6;
  const int row0 = blockIdx.x * BM;

  // B ds_read addressing: n = 64*wave + 16*nf + (lane&15); n&7 == lane&7.
  const int bbase = wave * 8192 + (lane & 15) * 128;
  const int sw0 = (((lane >> 4) ^ (lane & 7)) << 4);          // ks=0 swizzle
  const int sw1 = (((4 + (lane >> 4)) ^ (lane & 7)) << 4);    // ks=1 swizzle

  // A addressing: lane covers rows row0+16m+(lane&15), k-slice (lane>>4)*8
  const float* aptr0 = x + (size_t)(row0 + (lane & 15)) * D_FEAT + ((lane >> 4) << 3);
  const float* aptr1 = aptr0 + 16 * D_FEAT;

  f32x4 acc[2][4];
#pragma unroll
  for (int m = 0; m < 2; ++m)
#pragma unroll
    for (int n = 0; n < 4; ++n)
#pragma unroll
      for (int j = 0; j < 4; ++j) acc[m][n][j] = 0.0f;

  // ---- prologue: issue B(0) stage FIRST (count order matters!), then A(0) --
  {
    const char* wsrc = (const char*)Wb;
#pragma unroll
    for (int i = 0; i < 8; ++i) {
      int off = i * 4096 + wave * 1024;
      __builtin_amdgcn_global_load_lds(
          (const __attribute__((address_space(1))) void*)(wsrc + off + lane * 16),
          (__attribute__((address_space(3))) void*)(smem + off), 16, 0, 0);
    }
  }
  __builtin_amdgcn_sched_barrier(0);   // pin: B(0) issued before A(0)

  f32x4 a[2][2][2];                    // [m][ks][half], fp32 prefetch of tile kt
#pragma unroll
  for (int m = 0; m < 2; ++m) {
    const float* p = m ? aptr1 : aptr0;
#pragma unroll
    for (int ks = 0; ks < 2; ++ks) {
      a[m][ks][0] = *(const f32x4*)(p + ks * 32);
      a[m][ks][1] = *(const f32x4*)(p + ks * 32 + 4);
    }
  }

  for (int kt = 0; kt < K_ITERS; ++kt) {
    const char* cur = smem + (kt & 1) * 32768;

    // wait for B(kt) (oldest 8); leave the 8 A(kt) loads in flight
    asm volatile("s_waitcnt vmcnt(8)" ::: "memory");
    __builtin_amdgcn_sched_barrier(0);
    __builtin_amdgcn_s_barrier();
    __builtin_amdgcn_sched_barrier(0);

    // ---- issue B(kt+1) into the other buffer (safe: all waves past barrier)
    if (kt + 1 < K_ITERS) {
      const char* wsrc = (const char*)Wb + (size_t)(kt + 1) * W_TILE_BYTES;
      char* nxt = smem + ((kt + 1) & 1) * 32768;
#pragma unroll
      for (int i = 0; i < 8; ++i) {
        int off = i * 4096 + wave * 1024;
        __builtin_amdgcn_global_load_lds(
            (const __attribute__((address_space(1))) void*)(wsrc + off + lane * 16),
            (__attribute__((address_space(3))) void*)(nxt + off), 16, 0, 0);
      }
    }
    __builtin_amdgcn_sched_barrier(0);   // pin: B(kt+1) issued before A(kt+1)

    // ---- convert A(kt) to bf16 fragments (1 cvt_pk per 2 elements) --------
    s16x8 frag[2][2];
#pragma unroll
    for (int m = 0; m < 2; ++m)
#pragma unroll
      for (int ks = 0; ks < 2; ++ks) {
        union { u32x4 u; s16x8 s; } pk;
#pragma unroll
        for (int h = 0; h < 2; ++h) {
          pk.u[2 * h]     = cvt_pk(a[m][ks][h][0], a[m][ks][h][1]);
          pk.u[2 * h + 1] = cvt_pk(a[m][ks][h][2], a[m][ks][h][3]);
        }
        frag[m][ks] = pk.s;
      }

    // ---- prefetch A(kt+1): 8 loads, in flight across next barrier ---------
    if (kt + 1 < K_ITERS) {
      int ko = (kt + 1) * BK;
#pragma unroll
      for (int m = 0; m < 2; ++m) {
        const float* p = (m ? aptr1 : aptr0) + ko;
#pragma unroll
        for (int ks = 0; ks < 2; ++ks) {
          a[m][ks][0] = *(const f32x4*)(p + ks * 32);
          a[m][ks][1] = *(const f32x4*)(p + ks * 32 + 4);
        }
      }
    }

    // ---- compute: 2 ks x 4 col-frags; each B read feeds 2 MFMAs -----------
#pragma unroll
    for (int ks = 0; ks < 2; ++ks) {
      int sw = ks ? sw1 : sw0;
#pragma unroll
      for (int nf = 0; nf < 4; ++nf) {
        s16x8 b = *(const s16x8*)(cur + bbase + nf * 2048 + sw);
        acc[0][nf] = __builtin_amdgcn_mfma_f32_16x16x32_bf16(frag[0][ks], b, acc[0][nf], 0, 0, 0);
        acc[1][nf] = __builtin_amdgcn_mfma_f32_16x16x32_bf16(frag[1][ks], b, acc[1][nf], 0, 0, 0);
      }
    }
  }

  __syncthreads();   // full drain before smem reuse as Ls

  // ---- epilogue: logits -> LDS, column-major stride 33 ---------------------
  float* Ls = (float*)smem;            // Ls[col*33 + row], col < 248
  const int c0 = lane & 15;
  const int rq = (lane >> 4) << 2;
#pragma unroll
  for (int m = 0; m < 2; ++m)
#pragma unroll
    for (int nf = 0; nf < 4; ++nf) {
      int col = wave * 64 + nf * 16 + c0;
      if (col < N_OUT) {
#pragma unroll
        for (int i = 0; i < 4; ++i) Ls[col * 33 + m * 16 + rq + i] = acc[m][nf][i];
      }
    }
  __syncthreads();

  // 8 threads per row: part p owns root i=p entirely (u1, level-1, level-2).
  const int p = tid & 7;
  const int r = tid >> 3;              // 0..31
  float* orow = out + (size_t)(row0 + r) * N_OUT;

  float ui = Ls[p * 33 + r] + b_final[p];
  orow[p] = ui;

  // level-1: softmax over 6, then u2 = p1 * u1
  float lg[6];
  float mx = -1e30f;
#pragma unroll
  for (int c = 0; c < 6; ++c) {
    lg[c] = Ls[(8 + p * 6 + c) * 33 + r] + ui * wu1[p * 6 + c] + b1[p * 6 + c];
    mx = fmaxf(mx, lg[c]);
  }
  float s = 0.0f;
#pragma unroll
  for (int c = 0; c < 6; ++c) { lg[c] = __expf(lg[c] - mx); s += lg[c]; }
  float sc = ui / s;
  float u2v[6];
#pragma unroll
  for (int c = 0; c < 6; ++c) {
    u2v[c] = lg[c] * sc;
    orow[8 + p * 6 + c] = u2v[c];
  }

  // level-2: 6 groups of 4, u3 = p2 * u2
#pragma unroll
  for (int j = 0; j < 6; ++j) {
    int g = p * 6 + j;
    float ug = u2v[j];
    float l2[4];
    float m2 = -1e30f;
#pragma unroll
    for (int c = 0; c < 4; ++c) {
      l2[c] = Ls[(56 + g * 4 + c) * 33 + r] + ug * wu2[g * 4 + c] + b2[g * 4 + c];
      m2 = fmaxf(m2, l2[c]);
    }
    float s2 = 0.0f;
#pragma unroll
    for (int c = 0; c < 4; ++c) { l2[c] = __expf(l2[c] - m2); s2 += l2[c]; }
    float sc2 = ug / s2;
    f32x4 o;
#pragma unroll
    for (int c = 0; c < 4; ++c) o[c] = l2[c] * sc2;
    *(f32x4*)(orow + 56 + g * 4) = o;
  }
}

// ---------------------------------------------------------------------------
extern "C" void kernel_launch(void* const* d_in, const int* in_sizes, int n_in,
                              void* d_out, int out_size, void* d_ws, size_t ws_size,
                              hipStream_t stream) {
  const float* x   = (const float*)d_in[0];
  const float* Wf  = (const float*)d_in[1];
  const float* bf  = (const float*)d_in[2];
  const float* Wp1 = (const float*)d_in[3];
  const float* wu1 = (const float*)d_in[4];
  const float* b1  = (const float*)d_in[5];
  const float* Wp2 = (const float*)d_in[6];
  const float* wu2 = (const float*)d_in[7];
  const float* b2  = (const float*)d_in[8];
  float* out = (float*)d_out;
  unsigned short* Wb = (unsigned short*)d_ws;   // 655,360 B packed bf16 weights

  pack_w_kernel<<<1280, 256, 0, stream>>>(Wf, Wp1, Wp2, Wb);
  tree_head_kernel<<<16384 / BM, 256, 0, stream>>>(x, Wb, bf, wu1, b1, wu2, b2, out);
}

// Round 4
// 33.363 us; speedup vs baseline: 1.9984x; 1.9984x over previous
//
#include <hip/hip_runtime.h>
#include <stdint.h>
#include <stddef.h>

// Problem constants
#define D_FEAT 1280
#define N_PAD  256
#define N_OUT  248
#define BM     64
#define BK     64
#define K_ITERS 20
#define W_TILE_BYTES (N_PAD * BK * 2)   // 32 KB bf16 weight tile
#define A_TILE_BYTES (BM * BK * 4)      // 16 KB fp32 activation tile

typedef float f32x4 __attribute__((ext_vector_type(4)));
typedef short s16x8 __attribute__((ext_vector_type(8)));
typedef unsigned int u32x4 __attribute__((ext_vector_type(4)));

__device__ __forceinline__ unsigned short f2bf(float f) {
  union { float f; unsigned int u; } v; v.f = f;
  unsigned int r = (v.u + 0x7fffu + ((v.u >> 16) & 1u)) >> 16;
  return (unsigned short)r;
}

// one v_cvt_pk_bf16_f32: packs 2 fp32 -> 2 bf16 (RTNE), lo=a, hi=b
__device__ __forceinline__ unsigned int cvt_pk(float a, float b) {
  unsigned int r;
  asm("v_cvt_pk_bf16_f32 %0, %1, %2" : "=v"(r) : "v"(a), "v"(b));
  return r;
}

__device__ __forceinline__ void gload16(const void* g, void* l) {
  __builtin_amdgcn_global_load_lds(
      (const __attribute__((address_space(1))) void*)g,
      (__attribute__((address_space(3))) void*)l, 16, 0, 0);
}

// ---------------------------------------------------------------------------
// Pack W_final (D,8), Wp1 (8,D,6), Wp2 (8,6,D,4) into one bf16 matrix laid out
// exactly as the main kernel's LDS B-tiles expect (XOR swizzle pre-baked so
// global_load_lds is a LINEAR copy and ds_read_b128 is conflict-free).
// Tile kt: [n=0..255][s_phys=0..7] 16B chunks; chunk(n,s_phys) holds
// W[n][kt*64 + 8*(s_phys ^ (n&7)) .. +7].
// ---------------------------------------------------------------------------
__global__ __launch_bounds__(256) void pack_w_kernel(
    const float* __restrict__ Wf, const float* __restrict__ Wp1,
    const float* __restrict__ Wp2, unsigned short* __restrict__ out) {
  int idx = blockIdx.x * 256 + threadIdx.x;    // 0 .. 327679
  int e = idx & 7;
  int chunk = idx >> 3;
  int s_phys = chunk & 7;
  int n = (chunk >> 3) & 255;
  int kt = chunk >> 11;
  int s_log = s_phys ^ (n & 7);
  int d = kt * BK + s_log * 8 + e;
  float v = 0.0f;
  if (n < 8) {
    v = Wf[d * 8 + n];
  } else if (n < 56) {
    int m = n - 8;
    v = Wp1[((m / 6) * D_FEAT + d) * 6 + (m % 6)];
  } else if (n < 248) {
    int m = n - 56;
    v = Wp2[(((m / 24) * 6 + ((m % 24) >> 2)) * D_FEAT + d) * 4 + (m & 3)];
  }
  out[idx] = f2bf(v);
}

// ---------------------------------------------------------------------------
// Fused GEMM (bf16 MFMA) + hierarchical softmax epilogue.
// 512 threads = 8 waves (2M x 4N): wave tile = 32 rows x 64 cols.
// A: fp32 staged in LDS via global_load_lds with slot^(row&15) source
//    pre-swizzle (conflict-free fragment reads), converted in-reg to bf16.
// B: bf16, pre-swizzled in global by pack_w_kernel.
// Pipeline: 2-deep, 3 LDS buffers, branch-free counted s_waitcnt vmcnt(6)
// (6 stage instrs/wave/tile), raw s_barrier; tails peeled. NO plain global
// loads inside the loop, so the compiler never inserts its own vmcnt.
// ---------------------------------------------------------------------------
__global__ __launch_bounds__(512, 2) void tree_head_kernel(
    const float* __restrict__ x, const unsigned short* __restrict__ Wb,
    const float* __restrict__ b_final, const float* __restrict__ wu1,
    const float* __restrict__ b1, const float* __restrict__ wu2,
    const float* __restrict__ b2, float* __restrict__ out) {
  __shared__ __align__(16) char smem[147456];  // 3x16KB A + 3x32KB B
  char* A0 = smem;
  char* A1 = smem + 16384;
  char* A2 = smem + 32768;
  char* B0 = smem + 49152;
  char* B1 = smem + 81920;
  char* B2 = smem + 114688;

  const int tid  = threadIdx.x;
  const int lane = tid & 63;
  const int wave = tid >> 6;       // 0..7
  const int wm   = wave >> 2;      // 0..1 (M half)
  const int wn   = wave & 3;       // 0..3 (N quarter)
  const int l15  = lane & 15;
  const int lh   = lane >> 4;      // 0..3
  const int row0 = blockIdx.x * BM;

  f32x4 acc[2][4];
#pragma unroll
  for (int m = 0; m < 2; ++m)
#pragma unroll
    for (int n = 0; n < 4; ++n)
#pragma unroll
      for (int j = 0; j < 4; ++j) acc[m][n][j] = 0.0f;

  // Per-lane A staging sources (2 global_load_lds per wave per tile).
  // Instr q = wave*2+j covers rows 4q..4q+3; lane: row=4q+lh, phys slot=l15,
  // logical slot = l15 ^ (row&15)  ->  LDS[row][phys] = x[row][phys^(row&15)].
  const char* asrc[2];
  int adst[2];
#pragma unroll
  for (int j = 0; j < 2; ++j) {
    int q = wave * 2 + j;
    int rl = 4 * q + lh;
    asrc[j] = (const char*)x + (size_t)(row0 + rl) * (D_FEAT * 4)
              + ((l15 ^ (rl & 15)) << 4);
    adst[j] = q * 1024;
  }
  const char* bsrc = (const char*)Wb + wave * 4096 + lane * 16;
  const int bdst = wave * 4096;

#define STAGE(kt_, dA, dB) do {                                               \
    _Pragma("unroll")                                                         \
    for (int j_ = 0; j_ < 4; ++j_)                                            \
      gload16(bsrc + (size_t)(kt_) * W_TILE_BYTES + j_ * 1024,                \
              (dB) + bdst + j_ * 1024);                                       \
    _Pragma("unroll")                                                         \
    for (int j_ = 0; j_ < 2; ++j_)                                            \
      gload16(asrc[j_] + (kt_) * 256, (dA) + adst[j_]);                       \
  } while (0)

#define COMPUTE(cA, cB) do {                                                  \
    s16x8 fr[2][2];                                                           \
    _Pragma("unroll")                                                         \
    for (int m_ = 0; m_ < 2; ++m_) {                                          \
      int rl_ = wm * 32 + m_ * 16 + l15;                                      \
      const char* rb_ = (cA) + rl_ * 256;                                     \
      _Pragma("unroll")                                                       \
      for (int ks_ = 0; ks_ < 2; ++ks_) {                                     \
        int s0_ = ks_ * 8 + lh * 2;                                           \
        f32x4 f0_ = *(const f32x4*)(rb_ + ((s0_ ^ (rl_ & 15)) << 4));         \
        f32x4 f1_ = *(const f32x4*)(rb_ + (((s0_ + 1) ^ (rl_ & 15)) << 4));   \
        union { u32x4 u; s16x8 s; } pk_;                                      \
        pk_.u[0] = cvt_pk(f0_[0], f0_[1]); pk_.u[1] = cvt_pk(f0_[2], f0_[3]); \
        pk_.u[2] = cvt_pk(f1_[0], f1_[1]); pk_.u[3] = cvt_pk(f1_[2], f1_[3]); \
        fr[m_][ks_] = pk_.s;                                                  \
      }                                                                       \
    }                                                                         \
    _Pragma("unroll")                                                         \
    for (int ks_ = 0; ks_ < 2; ++ks_) {                                       \
      int sl_ = ks_ * 4 + lh;                                                 \
      _Pragma("unroll")                                                       \
      for (int nf_ = 0; nf_ < 4; ++nf_) {                                     \
        int n_ = wn * 64 + nf_ * 16 + l15;                                    \
        s16x8 b_ = *(const s16x8*)((cB) + n_ * 128 + ((sl_ ^ (n_ & 7)) << 4));\
        acc[0][nf_] = __builtin_amdgcn_mfma_f32_16x16x32_bf16(fr[0][ks_], b_, acc[0][nf_], 0, 0, 0); \
        acc[1][nf_] = __builtin_amdgcn_mfma_f32_16x16x32_bf16(fr[1][ks_], b_, acc[1][nf_], 0, 0, 0); \
      }                                                                       \
    }                                                                         \
  } while (0)

#define ITER_MAIN(kt_, cA, cB, nA, nB) do {                                   \
    asm volatile("s_waitcnt vmcnt(6)" ::: "memory");                          \
    __builtin_amdgcn_sched_barrier(0);                                        \
    __builtin_amdgcn_s_barrier();                                             \
    __builtin_amdgcn_sched_barrier(0);                                        \
    STAGE((kt_) + 2, nA, nB);                                                 \
    __builtin_amdgcn_sched_barrier(0);                                        \
    COMPUTE(cA, cB);                                                          \
  } while (0)

  // ---- prologue: 2-deep prefetch ------------------------------------------
  STAGE(0, A0, B0);
  STAGE(1, A1, B1);

  // ---- main loop: kt = 0..17, buffers rotate (0,1,2), stage kt+2 ----------
  for (int t = 0; t < 6; ++t) {
    int kt = 3 * t;
    ITER_MAIN(kt,     A0, B0, A2, B2);
    ITER_MAIN(kt + 1, A1, B1, A0, B0);
    ITER_MAIN(kt + 2, A2, B2, A1, B1);
  }

  // ---- peeled tails: kt = 18 (buf0), kt = 19 (buf1), no staging -----------
  asm volatile("s_waitcnt vmcnt(6)" ::: "memory");
  __builtin_amdgcn_sched_barrier(0);
  __builtin_amdgcn_s_barrier();
  __builtin_amdgcn_sched_barrier(0);
  COMPUTE(A0, B0);

  asm volatile("s_waitcnt vmcnt(0)" ::: "memory");
  __builtin_amdgcn_sched_barrier(0);
  __builtin_amdgcn_s_barrier();
  __builtin_amdgcn_sched_barrier(0);
  COMPUTE(A1, B1);

  __syncthreads();   // full drain before smem reuse as Ls

  // ---- epilogue: logits -> LDS, column-major stride 65 --------------------
  float* Ls = (float*)smem;            // Ls[col*65 + row], col<248 (64.5 KB)
#pragma unroll
  for (int m = 0; m < 2; ++m)
#pragma unroll
    for (int nf = 0; nf < 4; ++nf) {
      int col = wn * 64 + nf * 16 + l15;
      if (col < N_OUT) {
        int rbase = wm * 32 + m * 16 + (lh << 2);
#pragma unroll
        for (int i = 0; i < 4; ++i) Ls[col * 65 + rbase + i] = acc[m][nf][i];
      }
    }
  __syncthreads();

  // 8 threads per row: part p owns root i=p entirely (u1, level-1, level-2).
  const int p = tid & 7;
  const int r = tid >> 3;              // 0..63
  float* orow = out + (size_t)(row0 + r) * N_OUT;

  float ui = Ls[p * 65 + r] + b_final[p];
  orow[p] = ui;

  // level-1: softmax over 6, then u2 = p1 * u1
  float lg[6];
  float mx = -1e30f;
#pragma unroll
  for (int c = 0; c < 6; ++c) {
    lg[c] = Ls[(8 + p * 6 + c) * 65 + r] + ui * wu1[p * 6 + c] + b1[p * 6 + c];
    mx = fmaxf(mx, lg[c]);
  }
  float s = 0.0f;
#pragma unroll
  for (int c = 0; c < 6; ++c) { lg[c] = __expf(lg[c] - mx); s += lg[c]; }
  float sc = ui / s;
  float u2v[6];
#pragma unroll
  for (int c = 0; c < 6; ++c) {
    u2v[c] = lg[c] * sc;
    orow[8 + p * 6 + c] = u2v[c];
  }

  // level-2: 6 groups of 4, u3 = p2 * u2
#pragma unroll
  for (int j = 0; j < 6; ++j) {
    int g = p * 6 + j;
    float ug = u2v[j];
    float l2[4];
    float m2 = -1e30f;
#pragma unroll
    for (int c = 0; c < 4; ++c) {
      l2[c] = Ls[(56 + g * 4 + c) * 65 + r] + ug * wu2[g * 4 + c] + b2[g * 4 + c];
      m2 = fmaxf(m2, l2[c]);
    }
    float s2 = 0.0f;
#pragma unroll
    for (int c = 0; c < 4; ++c) { l2[c] = __expf(l2[c] - m2); s2 += l2[c]; }
    float sc2 = ug / s2;
    f32x4 o;
#pragma unroll
    for (int c = 0; c < 4; ++c) o[c] = l2[c] * sc2;
    *(f32x4*)(orow + 56 + g * 4) = o;
  }
#undef STAGE
#undef COMPUTE
#undef ITER_MAIN
}

// ---------------------------------------------------------------------------
extern "C" void kernel_launch(void* const* d_in, const int* in_sizes, int n_in,
                              void* d_out, int out_size, void* d_ws, size_t ws_size,
                              hipStream_t stream) {
  const float* x   = (const float*)d_in[0];
  const float* Wf  = (const float*)d_in[1];
  const float* bf  = (const float*)d_in[2];
  const float* Wp1 = (const float*)d_in[3];
  const float* wu1 = (const float*)d_in[4];
  const float* b1  = (const float*)d_in[5];
  const float* Wp2 = (const float*)d_in[6];
  const float* wu2 = (const float*)d_in[7];
  const float* b2  = (const float*)d_in[8];
  float* out = (float*)d_out;
  unsigned short* Wb = (unsigned short*)d_ws;   // 655,360 B packed bf16 weights

  pack_w_kernel<<<1280, 256, 0, stream>>>(Wf, Wp1, Wp2, Wb);
  tree_head_kernel<<<16384 / BM, 512, 0, stream>>>(x, Wb, bf, wu1, b1, wu2, b2, out);
}